// Round 1
// baseline (401.761 us; speedup 1.0000x reference)
//
#include <hip/hip_runtime.h>
#include <hip/hip_bf16.h>

#define B_ 2
#define S_ 2048
#define H_ 16
#define DQ_ 192
#define DV_ 128
#define SCALE 0.07216878364870322f   // 1/sqrt(192)

typedef short short8 __attribute__((ext_vector_type(8)));
typedef float f32x4 __attribute__((ext_vector_type(4)));

__device__ __forceinline__ unsigned short f2bf(float f) {
  union { float f; unsigned u; } x; x.f = f;
  unsigned r = x.u + 0x7FFFu + ((x.u >> 16) & 1u);   // RNE
  return (unsigned short)(r >> 16);
}

__launch_bounds__(256)
__global__ void mla_fwd(const float* __restrict__ Q,
                        const float* __restrict__ K,
                        const float* __restrict__ V,
                        float* __restrict__ O) {
  // K tile: 32 rows x 192 d, +8 pad -> row stride 400B (conflict-free b128 frags)
  __shared__ __align__(16) unsigned short Kl[32][200];
  // V transposed: Vt[dv][k], +8 pad -> row stride 80B
  __shared__ __align__(16) unsigned short Vt[128][40];
  // per-wave P: [16 q][32 k] +8 pad
  __shared__ __align__(16) unsigned short Pl[4][16][40];

  const int tid  = threadIdx.x;
  const int wid  = tid >> 6;
  const int lane = tid & 63;
  const int l15  = lane & 15;
  const int g    = lane >> 4;

  const int qtile = blockIdx.x;   // 0..31
  const int bh    = blockIdx.y;   // 0..31
  const int b     = bh >> 4;
  const int h     = bh & 15;

  const int q0w = qtile * 64 + wid * 16;   // wave's q base

  // Hoist Q fragments: a[j] = Q[q0w + l15][d0*32 + g*8 + j]  (bf16)
  short8 aq[6];
  {
    const int qoff = ((b * S_ + (q0w + l15)) * H_ + h) * DQ_;
    #pragma unroll
    for (int d0 = 0; d0 < 6; ++d0) {
      const float* p = Q + qoff + d0 * 32 + g * 8;
      float4 f0 = *(const float4*)(p);
      float4 f1 = *(const float4*)(p + 4);
      short8 a;
      a[0] = f2bf(f0.x); a[1] = f2bf(f0.y); a[2] = f2bf(f0.z); a[3] = f2bf(f0.w);
      a[4] = f2bf(f1.x); a[5] = f2bf(f1.y); a[6] = f2bf(f1.z); a[7] = f2bf(f1.w);
      aq[d0] = a;
    }
  }

  f32x4 o[8];
  #pragma unroll
  for (int t = 0; t < 8; ++t) o[t] = (f32x4)0.0f;
  float m[4], l[4];
  #pragma unroll
  for (int r = 0; r < 4; ++r) { m[r] = -1e30f; l[r] = 0.0f; }

  const int ntiles = qtile * 2 + 2;
  for (int kt = 0; kt < ntiles; ++kt) {
    const int kbase = kt * 32;
    __syncthreads();   // protect LDS overwrite vs previous iteration's reads

    // ---- stage K tile: 32x192 f32 -> bf16 LDS (coalesced float4 reads) ----
    #pragma unroll
    for (int i = 0; i < 6; ++i) {
      int idx = i * 256 + tid;
      int row = idx / 48, col4 = idx % 48;
      const float4 kv = *(const float4*)(K + ((b * S_ + kbase + row) * H_ + h) * DQ_ + col4 * 4);
      ushort4 u;
      u.x = f2bf(kv.x); u.y = f2bf(kv.y); u.z = f2bf(kv.z); u.w = f2bf(kv.w);
      *(ushort4*)&Kl[row][col4 * 4] = u;
    }
    // ---- stage V transposed: Vt[dv][k] (k varies across lanes -> conflict-free writes) ----
    #pragma unroll
    for (int i = 0; i < 4; ++i) {
      int idx = i * 256 + tid;
      int krow = idx & 31, col4 = idx >> 5;
      const float4 vv = *(const float4*)(V + ((b * S_ + kbase + krow) * H_ + h) * DV_ + col4 * 4);
      Vt[col4 * 4 + 0][krow] = f2bf(vv.x);
      Vt[col4 * 4 + 1][krow] = f2bf(vv.y);
      Vt[col4 * 4 + 2][krow] = f2bf(vv.z);
      Vt[col4 * 4 + 3][krow] = f2bf(vv.w);
    }
    __syncthreads();

    // ---- QK^T: S[16q x 32k], two 16-col subtiles ----
    f32x4 sa[2];
    sa[0] = (f32x4)0.0f; sa[1] = (f32x4)0.0f;
    #pragma unroll
    for (int kc = 0; kc < 2; ++kc) {
      #pragma unroll
      for (int d0 = 0; d0 < 6; ++d0) {
        short8 bk = *(const short8*)&Kl[kc * 16 + l15][d0 * 32 + g * 8];
        sa[kc] = __builtin_amdgcn_mfma_f32_16x16x32_bf16(aq[d0], bk, sa[kc], 0, 0, 0);
      }
    }

    // ---- scale + causal mask + online softmax ----
    float pv[2][4], rm[4];
    #pragma unroll
    for (int r = 0; r < 4; ++r) {
      const int qg = q0w + 4 * g + r;       // this lane's row (reg r)
      float s0 = sa[0][r] * SCALE;
      float s1 = sa[1][r] * SCALE;
      if (kbase + l15 > qg)      s0 = -1e30f;
      if (kbase + 16 + l15 > qg) s1 = -1e30f;
      pv[0][r] = s0; pv[1][r] = s1;
      rm[r] = fmaxf(s0, s1);
    }
    #pragma unroll
    for (int r = 0; r < 4; ++r) {
      #pragma unroll
      for (int off = 1; off < 16; off <<= 1)
        rm[r] = fmaxf(rm[r], __shfl_xor(rm[r], off));
    }
    float alpha[4];
    #pragma unroll
    for (int r = 0; r < 4; ++r) {
      float mn = fmaxf(m[r], rm[r]);
      alpha[r] = expf(m[r] - mn);
      m[r] = mn;
      float p0 = expf(pv[0][r] - mn);
      float p1 = expf(pv[1][r] - mn);
      pv[0][r] = p0; pv[1][r] = p1;
      float rs = p0 + p1;
      #pragma unroll
      for (int off = 1; off < 16; off <<= 1)
        rs += __shfl_xor(rs, off);
      l[r] = l[r] * alpha[r] + rs;
      #pragma unroll
      for (int t = 0; t < 8; ++t) o[t][r] *= alpha[r];
    }

    // ---- P -> LDS (re-layout to A-fragments) ----
    #pragma unroll
    for (int kc = 0; kc < 2; ++kc)
      #pragma unroll
      for (int r = 0; r < 4; ++r)
        Pl[wid][4 * g + r][kc * 16 + l15] = f2bf(pv[kc][r]);
    __syncthreads();   // safe ordering for P (and keeps barrier count uniform)

    // ---- PV: O += P[16x32] * V[32x128] ----
    short8 pa = *(const short8*)&Pl[wid][l15][g * 8];
    #pragma unroll
    for (int t = 0; t < 8; ++t) {
      short8 vb = *(const short8*)&Vt[t * 16 + l15][g * 8];
      o[t] = __builtin_amdgcn_mfma_f32_16x16x32_bf16(pa, vb, o[t], 0, 0, 0);
    }
  }

  // ---- epilogue: O[b][q][h][dv] = o / l ----
  #pragma unroll
  for (int r = 0; r < 4; ++r) {
    const int qg = q0w + 4 * g + r;
    const float inv = 1.0f / l[r];
    #pragma unroll
    for (int t = 0; t < 8; ++t)
      O[((b * S_ + qg) * H_ + h) * DV_ + t * 16 + l15] = o[t][r] * inv;
  }
}

extern "C" void kernel_launch(void* const* d_in, const int* in_sizes, int n_in,
                              void* d_out, int out_size, void* d_ws, size_t ws_size,
                              hipStream_t stream) {
  const float* q = (const float*)d_in[0];
  const float* k = (const float*)d_in[1];
  const float* v = (const float*)d_in[2];
  float* out = (float*)d_out;
  dim3 grid(S_ / 64, B_ * H_);
  dim3 block(256);
  mla_fwd<<<grid, block, 0, stream>>>(q, k, v, out);
}

// Round 2
// 325.211 us; speedup vs baseline: 1.2354x; 1.2354x over previous
//
#include <hip/hip_runtime.h>

#define B_ 2
#define S_ 2048
#define H_ 16
#define DQ_ 192
#define DV_ 128
// log2(e)/sqrt(192): scores kept in log2 domain so exp -> v_exp_f32
#define SCL2 0.10411163731422901f

typedef short short8 __attribute__((ext_vector_type(8)));
typedef float f32x4 __attribute__((ext_vector_type(4)));

__device__ __forceinline__ unsigned short f2bf(float f) {
  union { float f; unsigned u; } x; x.f = f;
  unsigned r = x.u + 0x7FFFu + ((x.u >> 16) & 1u);   // RNE
  return (unsigned short)(r >> 16);
}

__launch_bounds__(256)
__global__ void mla_fwd(const float* __restrict__ Q,
                        const float* __restrict__ K,
                        const float* __restrict__ V,
                        float* __restrict__ O) {
  // double-buffered K (32x192 bf16, +8 pad) and V^T (128 x 32, +8 pad)
  __shared__ __align__(16) unsigned short Kl[2][32][200];
  __shared__ __align__(16) unsigned short Vt[2][128][40];
  // per-wave P scratch (wave-local: no block barrier needed)
  __shared__ __align__(16) unsigned short Pl[4][16][40];

  const int tid  = threadIdx.x;
  const int wid  = tid >> 6;
  const int lane = tid & 63;
  const int l15  = lane & 15;
  const int g    = lane >> 4;

  // heavy blocks (large qtile) first -> shorter tail
  const int qtile = (int)gridDim.x - 1 - (int)blockIdx.x;
  const int bh    = blockIdx.y;
  const int b     = bh >> 4;
  const int h     = bh & 15;
  const int q0w   = qtile * 64 + wid * 16;

  const int krs = H_ * DQ_;   // K row stride (floats)
  const int vrs = H_ * DV_;   // V row stride

  // ---- hoist Q fragments: aq[d0][j] = Q[q0w+l15][d0*32 + g*8 + j] ----
  short8 aq[6];
  {
    const int qoff = ((b * S_ + (q0w + l15)) * H_ + h) * DQ_;
    #pragma unroll
    for (int d0 = 0; d0 < 6; ++d0) {
      const float* p = Q + qoff + d0 * 32 + g * 8;
      float4 f0 = *(const float4*)(p);
      float4 f1 = *(const float4*)(p + 4);
      short8 a;
      a[0] = f2bf(f0.x); a[1] = f2bf(f0.y); a[2] = f2bf(f0.z); a[3] = f2bf(f0.w);
      a[4] = f2bf(f1.x); a[5] = f2bf(f1.y); a[6] = f2bf(f1.z); a[7] = f2bf(f1.w);
      aq[d0] = a;
    }
  }

  f32x4 o[8];
  #pragma unroll
  for (int t = 0; t < 8; ++t) o[t] = (f32x4)0.0f;
  float m[4], l[4];
  #pragma unroll
  for (int r = 0; r < 4; ++r) { m[r] = -1e30f; l[r] = 0.0f; }

  const int ntiles = qtile * 2 + 2;

  float4 kr[6], vr[4];

  // ---- prologue: stage tile 0 into buf 0 ----
  {
    const float* Kb = K + ((b * S_) * H_ + h) * DQ_;
    #pragma unroll
    for (int i = 0; i < 6; ++i) {
      int idx = i * 256 + tid; int row = idx / 48, c4 = idx % 48;
      kr[i] = *(const float4*)(Kb + row * krs + c4 * 4);
    }
    const float* Vb = V + ((b * S_) * H_ + h) * DV_;
    #pragma unroll
    for (int i = 0; i < 4; ++i) {
      int idx = i * 256 + tid; int row = idx & 31, c4 = idx >> 5;
      vr[i] = *(const float4*)(Vb + row * vrs + c4 * 4);
    }
    #pragma unroll
    for (int i = 0; i < 6; ++i) {
      int idx = i * 256 + tid; int row = idx / 48, c4 = idx % 48;
      ushort4 u; u.x = f2bf(kr[i].x); u.y = f2bf(kr[i].y); u.z = f2bf(kr[i].z); u.w = f2bf(kr[i].w);
      *(ushort4*)&Kl[0][row][c4 * 4] = u;
    }
    #pragma unroll
    for (int i = 0; i < 4; ++i) {
      int idx = i * 256 + tid; int row = idx & 31, c4 = idx >> 5;
      Vt[0][c4 * 4 + 0][row] = f2bf(vr[i].x);
      Vt[0][c4 * 4 + 1][row] = f2bf(vr[i].y);
      Vt[0][c4 * 4 + 2][row] = f2bf(vr[i].z);
      Vt[0][c4 * 4 + 3][row] = f2bf(vr[i].w);
    }
  }
  __syncthreads();

  int cur = 0;
  for (int kt = 0; kt < ntiles; ++kt) {
    const int kbase = kt * 32;
    const bool pf = (kt + 1 < ntiles);

    // ---- issue next-tile global loads early (latency hides under compute) ----
    if (pf) {
      const int nb = kbase + 32;
      const float* Kb = K + ((b * S_ + nb) * H_ + h) * DQ_;
      #pragma unroll
      for (int i = 0; i < 6; ++i) {
        int idx = i * 256 + tid; int row = idx / 48, c4 = idx % 48;
        kr[i] = *(const float4*)(Kb + row * krs + c4 * 4);
      }
      const float* Vb = V + ((b * S_ + nb) * H_ + h) * DV_;
      #pragma unroll
      for (int i = 0; i < 4; ++i) {
        int idx = i * 256 + tid; int row = idx & 31, c4 = idx >> 5;
        vr[i] = *(const float4*)(Vb + row * vrs + c4 * 4);
      }
    }

    // ---- QK^T: S[16q x 32k] ----
    f32x4 sa0 = (f32x4)0.0f, sa1 = (f32x4)0.0f;
    #pragma unroll
    for (int d0 = 0; d0 < 6; ++d0) {
      short8 b0 = *(const short8*)&Kl[cur][l15][d0 * 32 + g * 8];
      sa0 = __builtin_amdgcn_mfma_f32_16x16x32_bf16(aq[d0], b0, sa0, 0, 0, 0);
      short8 b1 = *(const short8*)&Kl[cur][16 + l15][d0 * 32 + g * 8];
      sa1 = __builtin_amdgcn_mfma_f32_16x16x32_bf16(aq[d0], b1, sa1, 0, 0, 0);
    }

    // ---- scale (log2 domain) + causal mask + online softmax ----
    float p0[4], p1[4];
    #pragma unroll
    for (int r = 0; r < 4; ++r) {
      const int qg = q0w + 4 * g + r;
      float s0 = sa0[r] * SCL2;
      float s1 = sa1[r] * SCL2;
      if (kbase + l15 > qg)      s0 = -1e30f;
      if (kbase + 16 + l15 > qg) s1 = -1e30f;
      p0[r] = s0; p1[r] = s1;
    }
    #pragma unroll
    for (int r = 0; r < 4; ++r) {
      float rm = fmaxf(p0[r], p1[r]);
      #pragma unroll
      for (int off = 1; off < 16; off <<= 1)
        rm = fmaxf(rm, __shfl_xor(rm, off));
      float mn = fmaxf(m[r], rm);
      float alpha = exp2f(m[r] - mn);
      m[r] = mn;
      float e0 = exp2f(p0[r] - mn);
      float e1 = exp2f(p1[r] - mn);
      p0[r] = e0; p1[r] = e1;
      float rs = e0 + e1;
      #pragma unroll
      for (int off = 1; off < 16; off <<= 1)
        rs += __shfl_xor(rs, off);
      l[r] = l[r] * alpha + rs;
      #pragma unroll
      for (int t = 0; t < 8; ++t) o[t][r] *= alpha;
    }

    // ---- P -> wave-local LDS (no block barrier) ----
    #pragma unroll
    for (int r = 0; r < 4; ++r) {
      Pl[wid][4 * g + r][l15]      = f2bf(p0[r]);
      Pl[wid][4 * g + r][16 + l15] = f2bf(p1[r]);
    }
    short8 pa = *(const short8*)&Pl[wid][l15][g * 8];

    // ---- PV: O += P[16x32] * V[32x128] ----
    #pragma unroll
    for (int t = 0; t < 8; ++t) {
      short8 vb = *(const short8*)&Vt[cur][t * 16 + l15][g * 8];
      o[t] = __builtin_amdgcn_mfma_f32_16x16x32_bf16(pa, vb, o[t], 0, 0, 0);
    }

    // ---- write staged regs into the other buffer ----
    if (pf) {
      #pragma unroll
      for (int i = 0; i < 6; ++i) {
        int idx = i * 256 + tid; int row = idx / 48, c4 = idx % 48;
        ushort4 u; u.x = f2bf(kr[i].x); u.y = f2bf(kr[i].y); u.z = f2bf(kr[i].z); u.w = f2bf(kr[i].w);
        *(ushort4*)&Kl[cur ^ 1][row][c4 * 4] = u;
      }
      #pragma unroll
      for (int i = 0; i < 4; ++i) {
        int idx = i * 256 + tid; int row = idx & 31, c4 = idx >> 5;
        Vt[cur ^ 1][c4 * 4 + 0][row] = f2bf(vr[i].x);
        Vt[cur ^ 1][c4 * 4 + 1][row] = f2bf(vr[i].y);
        Vt[cur ^ 1][c4 * 4 + 2][row] = f2bf(vr[i].z);
        Vt[cur ^ 1][c4 * 4 + 3][row] = f2bf(vr[i].w);
      }
    }
    __syncthreads();
    cur ^= 1;
  }

  // ---- epilogue ----
  #pragma unroll
  for (int r = 0; r < 4; ++r) {
    const int qg = q0w + 4 * g + r;
    const float inv = 1.0f / l[r];
    #pragma unroll
    for (int t = 0; t < 8; ++t)
      O[((b * S_ + qg) * H_ + h) * DV_ + t * 16 + l15] = o[t][r] * inv;
  }
}

extern "C" void kernel_launch(void* const* d_in, const int* in_sizes, int n_in,
                              void* d_out, int out_size, void* d_ws, size_t ws_size,
                              hipStream_t stream) {
  const float* q = (const float*)d_in[0];
  const float* k = (const float*)d_in[1];
  const float* v = (const float*)d_in[2];
  float* out = (float*)d_out;
  dim3 grid(S_ / 64, B_ * H_);
  dim3 block(256);
  mla_fwd<<<grid, block, 0, stream>>>(q, k, v, out);
}

// Round 3
// 223.028 us; speedup vs baseline: 1.8014x; 1.4582x over previous
//
#include <hip/hip_runtime.h>

#define B_ 2
#define S_ 2048
#define H_ 16
#define DQ_ 192
#define DV_ 128
// log2(e)/sqrt(192)
#define SCL2 0.10411163731422901f

typedef short short8 __attribute__((ext_vector_type(8)));
typedef float f32x4 __attribute__((ext_vector_type(4)));

#define KG_BYTES ((size_t)25165824)   // B*H*S*DQ*2
#define VG_BYTES ((size_t)16777216)   // B*H*DV*S*2

__device__ __forceinline__ unsigned short f2bf(float f) {
  union { float f; unsigned u; } x; x.f = f;
  unsigned r = x.u + 0x7FFFu + ((x.u >> 16) & 1u);   // RNE
  return (unsigned short)(r >> 16);
}

#define GLL16(src, dst) \
  __builtin_amdgcn_global_load_lds((const __attribute__((address_space(1))) void*)(src), \
                                   (__attribute__((address_space(3))) void*)(dst), 16, 0, 0)

// ---------------- pre-pass: K -> bf16, row-swizzled [bh][s][384B] ----------------
__global__ __launch_bounds__(256) void prep_k(const float* __restrict__ K,
                                              unsigned short* __restrict__ Kg) {
  int idx = blockIdx.x * 256 + threadIdx.x;   // B*S*H*48 threads
  int d4 = idx % 48; int r = idx / 48;
  int h = r % H_; r /= H_;
  int s = r % S_; int b = r / S_;
  float4 f = *(const float4*)(K + (size_t)((b * S_ + s) * H_ + h) * DQ_ + d4 * 4);
  ushort4 u; u.x = f2bf(f.x); u.y = f2bf(f.y); u.z = f2bf(f.z); u.w = f2bf(f.w);
  size_t rowb = (size_t)((b * H_ + h) * S_ + s) * (DQ_ * 2);
  int cb = (d4 * 8) ^ ((s & 7) << 4);         // XOR-swizzle, bits 4..6, bijective in 384B row
  *(ushort4*)((char*)Kg + rowb + cb) = u;
}

// ------- pre-pass: V -> bf16, transposed+swizzled 8KB tiles [bh][sb][tile] -------
// tile byte (d>>1)*128 + (((d&1)*64 + (s%32)*2) ^ (((d>>1)&7)<<4)) holds V[s][d]
__global__ __launch_bounds__(256) void prep_v(const float* __restrict__ V,
                                              unsigned short* __restrict__ Vg) {
  __shared__ float lv[32][132];
  int blk = blockIdx.x;                 // bh*64 + sb
  int sb = blk & 63, bh = blk >> 6;
  int b = bh >> 4, h = bh & 15;
  int tid = threadIdx.x;
  #pragma unroll
  for (int i = 0; i < 4; ++i) {
    int idx = i * 256 + tid;            // 0..1023
    int s_in = idx >> 5, d4 = idx & 31;
    float4 f = *(const float4*)(V + (size_t)((b * S_ + sb * 32 + s_in) * H_ + h) * DV_ + d4 * 4);
    lv[s_in][d4 * 4 + 0] = f.x; lv[s_in][d4 * 4 + 1] = f.y;
    lv[s_in][d4 * 4 + 2] = f.z; lv[s_in][d4 * 4 + 3] = f.w;
  }
  __syncthreads();
  char* base = (char*)Vg + (size_t)blk * 8192;
  #pragma unroll
  for (int j = 0; j < 2; ++j) {
    int ob = tid * 32 + j * 16;         // output byte in tile, 16B chunk
    int row = ob >> 7, cb = ob & 127;
    int orig = cb ^ ((row & 7) << 4);   // un-swizzle
    int d = row * 2 + (orig >> 6);
    int s0 = (orig & 63) >> 1;          // 8 consecutive s
    short8 u;
    #pragma unroll
    for (int e = 0; e < 8; ++e) u[e] = (short)f2bf(lv[s0 + e][d]);
    *(short8*)(base + ob) = u;
  }
}

// ---------------- main: flash MLA, gll-staged bf16 K/V ----------------
__launch_bounds__(256)
__global__ void mla_fwd(const float* __restrict__ Q,
                        const unsigned short* __restrict__ Kg,
                        const unsigned short* __restrict__ Vg,
                        float* __restrict__ O) {
  __shared__ __align__(16) unsigned char KB[2][12288];   // 32 x 384B swizzled rows
  __shared__ __align__(16) unsigned char VB[2][8192];    // transposed+swizzled V tile
  __shared__ __align__(16) unsigned short Pl[4][16][40]; // per-wave P scratch

  const int tid  = threadIdx.x;
  const int wid  = tid >> 6;
  const int lane = tid & 63;
  const int l15  = lane & 15;
  const int g    = lane >> 4;

  // XCD-grouped mapping: XCD x gets bh = x*4 + (y>>5); heavy qtiles first
  const int i   = blockIdx.x;
  const int x   = i & 7, y = i >> 3;
  const int bh  = x * 4 + (y >> 5);
  const int qtile = 31 - (y & 31);
  const int b   = bh >> 4, h = bh & 15;
  const int q0w = qtile * 64 + wid * 16;

  const char* kg_bh = (const char*)Kg + (size_t)bh * S_ * (DQ_ * 2);
  const char* vg_bh = (const char*)Vg + (size_t)bh * 64 * 8192;

  // ---- hoist Q fragments (f32 -> bf16 once) ----
  short8 aq[6];
  {
    const size_t qoff = (size_t)((b * S_ + (q0w + l15)) * H_ + h) * DQ_;
    #pragma unroll
    for (int d0 = 0; d0 < 6; ++d0) {
      const float* p = Q + qoff + d0 * 32 + g * 8;
      float4 f0 = *(const float4*)(p);
      float4 f1 = *(const float4*)(p + 4);
      short8 a;
      a[0] = f2bf(f0.x); a[1] = f2bf(f0.y); a[2] = f2bf(f0.z); a[3] = f2bf(f0.w);
      a[4] = f2bf(f1.x); a[5] = f2bf(f1.y); a[6] = f2bf(f1.z); a[7] = f2bf(f1.w);
      aq[d0] = a;
    }
  }

  f32x4 o[8];
  #pragma unroll
  for (int t = 0; t < 8; ++t) o[t] = (f32x4)0.0f;
  float m[4], l[4];
  #pragma unroll
  for (int r = 0; r < 4; ++r) { m[r] = -1e30f; l[r] = 0.0f; }

  // hoisted per-lane addressing
  const int kxor = (l15 & 7) << 4;
  const int g16  = g * 16;
  const int vlane = (l15 >> 1) * 128 + ((((l15 & 1) * 64) + g16) ^ (((l15 >> 1) & 7) << 4));

  const int ntiles = qtile * 2 + 2;

  // ---- staging: 20 x 1KB chunks (K:12, V:8), 5 per wave, pure global_load_lds ----
  #define STAGE(buf, kt)                                                          \
    do {                                                                          \
      const char* ksrc = kg_bh + (size_t)(kt) * 32 * 384;                         \
      const char* vsrc = vg_bh + (size_t)(kt) * 8192;                             \
      _Pragma("unroll")                                                           \
      for (int c = 0; c < 5; ++c) {                                               \
        int cc = wid * 5 + c;                                                     \
        if (cc < 12) GLL16(ksrc + cc * 1024 + lane * 16, &KB[buf][cc * 1024]);    \
        else         GLL16(vsrc + (cc - 12) * 1024 + lane * 16,                   \
                           &VB[buf][(cc - 12) * 1024]);                           \
      }                                                                           \
    } while (0)

  STAGE(0, 0);
  __syncthreads();

  int cur = 0;
  for (int kt = 0; kt < ntiles; ++kt) {
    const int kbase = kt * 32;
    if (kt + 1 < ntiles) STAGE(cur ^ 1, kt + 1);

    // ---- QK^T: S[16q x 32k] ----
    const char* k0 = (const char*)&KB[cur][0] + l15 * 384;
    const char* k1 = k0 + 16 * 384;
    f32x4 sa0 = (f32x4)0.0f, sa1 = (f32x4)0.0f;
    #pragma unroll
    for (int d0 = 0; d0 < 6; ++d0) {
      const int col = (d0 * 64 + g16) ^ kxor;
      short8 b0 = *(const short8*)(k0 + col);
      sa0 = __builtin_amdgcn_mfma_f32_16x16x32_bf16(aq[d0], b0, sa0, 0, 0, 0);
      short8 b1 = *(const short8*)(k1 + col);
      sa1 = __builtin_amdgcn_mfma_f32_16x16x32_bf16(aq[d0], b1, sa1, 0, 0, 0);
    }

    // ---- scale + causal mask + online softmax ----
    float p0[4], p1[4];
    #pragma unroll
    for (int r = 0; r < 4; ++r) {
      const int qg = q0w + 4 * g + r;
      float s0 = sa0[r] * SCL2;
      float s1 = sa1[r] * SCL2;
      if (kbase + l15 > qg)      s0 = -1e30f;
      if (kbase + 16 + l15 > qg) s1 = -1e30f;
      p0[r] = s0; p1[r] = s1;
    }
    #pragma unroll
    for (int r = 0; r < 4; ++r) {
      float rm = fmaxf(p0[r], p1[r]);
      #pragma unroll
      for (int off = 1; off < 16; off <<= 1)
        rm = fmaxf(rm, __shfl_xor(rm, off));
      float mn = fmaxf(m[r], rm);
      float alpha = exp2f(m[r] - mn);
      m[r] = mn;
      float e0 = exp2f(p0[r] - mn);
      float e1 = exp2f(p1[r] - mn);
      p0[r] = e0; p1[r] = e1;
      float rs = e0 + e1;
      #pragma unroll
      for (int off = 1; off < 16; off <<= 1)
        rs += __shfl_xor(rs, off);
      l[r] = l[r] * alpha + rs;
      #pragma unroll
      for (int t = 0; t < 8; ++t) o[t][r] *= alpha;
    }

    // ---- P -> wave-local LDS re-layout ----
    #pragma unroll
    for (int r = 0; r < 4; ++r) {
      Pl[wid][4 * g + r][l15]      = f2bf(p0[r]);
      Pl[wid][4 * g + r][16 + l15] = f2bf(p1[r]);
    }
    short8 pa = *(const short8*)&Pl[wid][l15][g * 8];

    // ---- PV ----
    const char* vbp = (const char*)&VB[cur][0] + vlane;
    #pragma unroll
    for (int t = 0; t < 8; ++t) {
      short8 vb = *(const short8*)(vbp + t * 1024);
      o[t] = __builtin_amdgcn_mfma_f32_16x16x32_bf16(pa, vb, o[t], 0, 0, 0);
    }

    __syncthreads();   // implicit vmcnt(0) drains the 5 gll issued at iter top
    cur ^= 1;
  }

  // ---- epilogue ----
  #pragma unroll
  for (int r = 0; r < 4; ++r) {
    const int qg = q0w + 4 * g + r;
    const float inv = 1.0f / l[r];
    #pragma unroll
    for (int t = 0; t < 8; ++t)
      O[(size_t)((b * S_ + qg) * H_ + h) * DV_ + t * 16 + l15] = o[t][r] * inv;
  }
  #undef STAGE
}

// ---------------- fallback (R2 kernel) if ws too small ----------------
__launch_bounds__(256)
__global__ void mla_fwd_fb(const float* __restrict__ Q,
                           const float* __restrict__ K,
                           const float* __restrict__ V,
                           float* __restrict__ O) {
  __shared__ __align__(16) unsigned short Kl[2][32][200];
  __shared__ __align__(16) unsigned short Vt[2][128][40];
  __shared__ __align__(16) unsigned short Pl[4][16][40];
  const int tid = threadIdx.x, wid = tid >> 6, lane = tid & 63;
  const int l15 = lane & 15, g = lane >> 4;
  const int qtile = (int)gridDim.x - 1 - (int)blockIdx.x;
  const int bh = blockIdx.y, b = bh >> 4, h = bh & 15;
  const int q0w = qtile * 64 + wid * 16;
  const int krs = H_ * DQ_, vrs = H_ * DV_;
  short8 aq[6];
  {
    const int qoff = ((b * S_ + (q0w + l15)) * H_ + h) * DQ_;
    #pragma unroll
    for (int d0 = 0; d0 < 6; ++d0) {
      const float* p = Q + qoff + d0 * 32 + g * 8;
      float4 f0 = *(const float4*)(p); float4 f1 = *(const float4*)(p + 4);
      short8 a;
      a[0]=f2bf(f0.x); a[1]=f2bf(f0.y); a[2]=f2bf(f0.z); a[3]=f2bf(f0.w);
      a[4]=f2bf(f1.x); a[5]=f2bf(f1.y); a[6]=f2bf(f1.z); a[7]=f2bf(f1.w);
      aq[d0] = a;
    }
  }
  f32x4 o[8];
  #pragma unroll
  for (int t = 0; t < 8; ++t) o[t] = (f32x4)0.0f;
  float m[4], l[4];
  #pragma unroll
  for (int r = 0; r < 4; ++r) { m[r] = -1e30f; l[r] = 0.0f; }
  const int ntiles = qtile * 2 + 2;
  float4 kr[6], vr[4];
  {
    const float* Kb = K + ((b * S_) * H_ + h) * DQ_;
    #pragma unroll
    for (int i = 0; i < 6; ++i) { int idx = i*256+tid; int row = idx/48, c4 = idx%48;
      kr[i] = *(const float4*)(Kb + row*krs + c4*4); }
    const float* Vb = V + ((b * S_) * H_ + h) * DV_;
    #pragma unroll
    for (int i = 0; i < 4; ++i) { int idx = i*256+tid; int row = idx&31, c4 = idx>>5;
      vr[i] = *(const float4*)(Vb + row*vrs + c4*4); }
    #pragma unroll
    for (int i = 0; i < 6; ++i) { int idx = i*256+tid; int row = idx/48, c4 = idx%48;
      ushort4 u; u.x=f2bf(kr[i].x); u.y=f2bf(kr[i].y); u.z=f2bf(kr[i].z); u.w=f2bf(kr[i].w);
      *(ushort4*)&Kl[0][row][c4*4] = u; }
    #pragma unroll
    for (int i = 0; i < 4; ++i) { int idx = i*256+tid; int row = idx&31, c4 = idx>>5;
      Vt[0][c4*4+0][row]=f2bf(vr[i].x); Vt[0][c4*4+1][row]=f2bf(vr[i].y);
      Vt[0][c4*4+2][row]=f2bf(vr[i].z); Vt[0][c4*4+3][row]=f2bf(vr[i].w); }
  }
  __syncthreads();
  int cur = 0;
  for (int kt = 0; kt < ntiles; ++kt) {
    const int kbase = kt * 32;
    const bool pf = (kt + 1 < ntiles);
    if (pf) {
      const int nb = kbase + 32;
      const float* Kb = K + ((b*S_+nb)*H_ + h)*DQ_;
      #pragma unroll
      for (int i = 0; i < 6; ++i) { int idx = i*256+tid; int row = idx/48, c4 = idx%48;
        kr[i] = *(const float4*)(Kb + row*krs + c4*4); }
      const float* Vb = V + ((b*S_+nb)*H_ + h)*DV_;
      #pragma unroll
      for (int i = 0; i < 4; ++i) { int idx = i*256+tid; int row = idx&31, c4 = idx>>5;
        vr[i] = *(const float4*)(Vb + row*vrs + c4*4); }
    }
    f32x4 sa0 = (f32x4)0.0f, sa1 = (f32x4)0.0f;
    #pragma unroll
    for (int d0 = 0; d0 < 6; ++d0) {
      short8 b0 = *(const short8*)&Kl[cur][l15][d0*32 + g*8];
      sa0 = __builtin_amdgcn_mfma_f32_16x16x32_bf16(aq[d0], b0, sa0, 0, 0, 0);
      short8 b1 = *(const short8*)&Kl[cur][16+l15][d0*32 + g*8];
      sa1 = __builtin_amdgcn_mfma_f32_16x16x32_bf16(aq[d0], b1, sa1, 0, 0, 0);
    }
    float p0[4], p1[4];
    #pragma unroll
    for (int r = 0; r < 4; ++r) {
      const int qg = q0w + 4*g + r;
      float s0 = sa0[r]*SCL2, s1 = sa1[r]*SCL2;
      if (kbase + l15 > qg) s0 = -1e30f;
      if (kbase + 16 + l15 > qg) s1 = -1e30f;
      p0[r] = s0; p1[r] = s1;
    }
    #pragma unroll
    for (int r = 0; r < 4; ++r) {
      float rm = fmaxf(p0[r], p1[r]);
      #pragma unroll
      for (int off = 1; off < 16; off <<= 1) rm = fmaxf(rm, __shfl_xor(rm, off));
      float mn = fmaxf(m[r], rm);
      float alpha = exp2f(m[r] - mn); m[r] = mn;
      float e0 = exp2f(p0[r] - mn), e1 = exp2f(p1[r] - mn);
      p0[r] = e0; p1[r] = e1;
      float rs = e0 + e1;
      #pragma unroll
      for (int off = 1; off < 16; off <<= 1) rs += __shfl_xor(rs, off);
      l[r] = l[r]*alpha + rs;
      #pragma unroll
      for (int t = 0; t < 8; ++t) o[t][r] *= alpha;
    }
    #pragma unroll
    for (int r = 0; r < 4; ++r) {
      Pl[wid][4*g+r][l15]      = f2bf(p0[r]);
      Pl[wid][4*g+r][16+l15]   = f2bf(p1[r]);
    }
    short8 pa = *(const short8*)&Pl[wid][l15][g*8];
    #pragma unroll
    for (int t = 0; t < 8; ++t) {
      short8 vb = *(const short8*)&Vt[cur][t*16+l15][g*8];
      o[t] = __builtin_amdgcn_mfma_f32_16x16x32_bf16(pa, vb, o[t], 0, 0, 0);
    }
    if (pf) {
      #pragma unroll
      for (int i = 0; i < 6; ++i) { int idx = i*256+tid; int row = idx/48, c4 = idx%48;
        ushort4 u; u.x=f2bf(kr[i].x); u.y=f2bf(kr[i].y); u.z=f2bf(kr[i].z); u.w=f2bf(kr[i].w);
        *(ushort4*)&Kl[cur^1][row][c4*4] = u; }
      #pragma unroll
      for (int i = 0; i < 4; ++i) { int idx = i*256+tid; int row = idx&31, c4 = idx>>5;
        Vt[cur^1][c4*4+0][row]=f2bf(vr[i].x); Vt[cur^1][c4*4+1][row]=f2bf(vr[i].y);
        Vt[cur^1][c4*4+2][row]=f2bf(vr[i].z); Vt[cur^1][c4*4+3][row]=f2bf(vr[i].w); }
    }
    __syncthreads();
    cur ^= 1;
  }
  #pragma unroll
  for (int r = 0; r < 4; ++r) {
    const int qg = q0w + 4*g + r;
    const float inv = 1.0f / l[r];
    #pragma unroll
    for (int t = 0; t < 8; ++t)
      O[((b*S_+qg)*H_ + h)*DV_ + t*16 + l15] = o[t][r] * inv;
  }
}

extern "C" void kernel_launch(void* const* d_in, const int* in_sizes, int n_in,
                              void* d_out, int out_size, void* d_ws, size_t ws_size,
                              hipStream_t stream) {
  const float* q = (const float*)d_in[0];
  const float* k = (const float*)d_in[1];
  const float* v = (const float*)d_in[2];
  float* out = (float*)d_out;

  if (ws_size >= KG_BYTES + VG_BYTES) {
    unsigned short* Kg = (unsigned short*)d_ws;
    unsigned short* Vg = (unsigned short*)((char*)d_ws + KG_BYTES);
    prep_k<<<dim3((B_ * S_ * H_ * 48) / 256), dim3(256), 0, stream>>>(k, Kg);
    prep_v<<<dim3(B_ * H_ * 64), dim3(256), 0, stream>>>(v, Vg);
    mla_fwd<<<dim3(1024), dim3(256), 0, stream>>>(q, Kg, Vg, out);
  } else {
    dim3 grid(S_ / 64, B_ * H_);
    mla_fwd_fb<<<grid, dim3(256), 0, stream>>>(q, k, v, out);
  }
}

// Round 4
// 158.202 us; speedup vs baseline: 2.5395x; 1.4098x over previous
//
#include <hip/hip_runtime.h>

#define B_ 2
#define S_ 2048
#define H_ 16
#define DQ_ 192
#define DV_ 128
// log2(e)/sqrt(192)
#define SCL2 0.10411163731422901f

typedef short short8 __attribute__((ext_vector_type(8)));
typedef float f32x4 __attribute__((ext_vector_type(4)));

#define KG_BYTES ((size_t)25165824)   // B*H*S*DQ*2
#define VG_BYTES ((size_t)16777216)   // B*H*DV*S*2

__device__ __forceinline__ unsigned short f2bf(float f) {
  union { float f; unsigned u; } x; x.f = f;
  unsigned r = x.u + 0x7FFFu + ((x.u >> 16) & 1u);   // RNE
  return (unsigned short)(r >> 16);
}

__device__ __forceinline__ float hw_exp2(float x) {
  float r; asm("v_exp_f32 %0, %1" : "=v"(r) : "v"(x)); return r;
}
__device__ __forceinline__ unsigned cvtpk(float lo, float hi) {
  unsigned r; asm("v_cvt_pk_bf16_f32 %0, %1, %2" : "=v"(r) : "v"(lo), "v"(hi)); return r;
}

#define GLL16(src, dst) \
  __builtin_amdgcn_global_load_lds((const __attribute__((address_space(1))) void*)(src), \
                                   (__attribute__((address_space(3))) void*)(dst), 16, 0, 0)

// ---------------- pre-pass: K -> bf16, row-swizzled [bh][s][384B] ----------------
__global__ __launch_bounds__(256) void prep_k(const float* __restrict__ K,
                                              unsigned short* __restrict__ Kg) {
  int idx = blockIdx.x * 256 + threadIdx.x;
  int d4 = idx % 48; int r = idx / 48;
  int h = r % H_; r /= H_;
  int s = r % S_; int b = r / S_;
  float4 f = *(const float4*)(K + (size_t)((b * S_ + s) * H_ + h) * DQ_ + d4 * 4);
  ushort4 u; u.x = f2bf(f.x); u.y = f2bf(f.y); u.z = f2bf(f.z); u.w = f2bf(f.w);
  size_t rowb = (size_t)((b * H_ + h) * S_ + s) * (DQ_ * 2);
  int cb = (d4 * 8) ^ ((s & 7) << 4);
  *(ushort4*)((char*)Kg + rowb + cb) = u;
}

// ------- pre-pass: V -> bf16, transposed+swizzled 8KB tiles [bh][sb][tile] -------
__global__ __launch_bounds__(256) void prep_v(const float* __restrict__ V,
                                              unsigned short* __restrict__ Vg) {
  __shared__ float lv[32][132];
  int blk = blockIdx.x;
  int sb = blk & 63, bh = blk >> 6;
  int b = bh >> 4, h = bh & 15;
  int tid = threadIdx.x;
  #pragma unroll
  for (int i = 0; i < 4; ++i) {
    int idx = i * 256 + tid;
    int s_in = idx >> 5, d4 = idx & 31;
    float4 f = *(const float4*)(V + (size_t)((b * S_ + sb * 32 + s_in) * H_ + h) * DV_ + d4 * 4);
    lv[s_in][d4 * 4 + 0] = f.x; lv[s_in][d4 * 4 + 1] = f.y;
    lv[s_in][d4 * 4 + 2] = f.z; lv[s_in][d4 * 4 + 3] = f.w;
  }
  __syncthreads();
  char* base = (char*)Vg + (size_t)blk * 8192;
  #pragma unroll
  for (int j = 0; j < 2; ++j) {
    int ob = tid * 32 + j * 16;
    int row = ob >> 7, cb = ob & 127;
    int orig = cb ^ ((row & 7) << 4);
    int d = row * 2 + (orig >> 6);
    int s0 = (orig & 63) >> 1;
    short8 u;
    #pragma unroll
    for (int e = 0; e < 8; ++e) u[e] = (short)f2bf(lv[s0 + e][d]);
    *(short8*)(base + ob) = u;
  }
}

// ---------------- main: flash MLA, swapped-operand QK^T, in-register softmax ----------------
__launch_bounds__(256, 4)
__global__ void mla_fwd(const float* __restrict__ Q,
                        const unsigned short* __restrict__ Kg,
                        const unsigned short* __restrict__ Vg,
                        float* __restrict__ O) {
  __shared__ __align__(16) unsigned char KB[2][12288];   // 32 x 384B swizzled rows
  __shared__ __align__(16) unsigned char VB[2][8192];    // transposed+swizzled V tile
  // total LDS = 40960 -> 4 blocks/CU

  const int tid  = threadIdx.x;
  const int wid  = tid >> 6;
  const int lane = tid & 63;
  const int l15  = lane & 15;
  const int g    = lane >> 4;

  const int i   = blockIdx.x;
  const int x   = i & 7, y = i >> 3;
  const int bh  = x * 4 + (y >> 5);
  const int qtile = 31 - (y & 31);
  const int b   = bh >> 4, h = bh & 15;
  const int q0w = qtile * 64 + wid * 16;

  const char* kg_bh = (const char*)Kg + (size_t)bh * S_ * (DQ_ * 2);
  const char* vg_bh = (const char*)Vg + (size_t)bh * 64 * 8192;

  // ---- hoist Q fragments (B-operand of swapped QK^T) ----
  short8 aq[6];
  {
    const size_t qoff = (size_t)((b * S_ + (q0w + l15)) * H_ + h) * DQ_;
    #pragma unroll
    for (int d0 = 0; d0 < 6; ++d0) {
      const float* p = Q + qoff + d0 * 32 + g * 8;
      float4 f0 = *(const float4*)(p);
      float4 f1 = *(const float4*)(p + 4);
      short8 a;
      a[0] = f2bf(f0.x); a[1] = f2bf(f0.y); a[2] = f2bf(f0.z); a[3] = f2bf(f0.w);
      a[4] = f2bf(f1.x); a[5] = f2bf(f1.y); a[6] = f2bf(f1.z); a[7] = f2bf(f1.w);
      aq[d0] = a;
    }
  }

  f32x4 o[8];   // O^T: o[t][r] = O[dv=16t+4g+r][q=l15]
  #pragma unroll
  for (int t = 0; t < 8; ++t) o[t] = (f32x4)0.0f;
  float m = -1e30f, l = 0.0f;

  const int kxor = (l15 & 7) << 4;
  const int g16  = g * 16;
  const int vlane = (l15 >> 1) * 128 + ((((l15 & 1) * 64) + g16) ^ (((l15 >> 1) & 7) << 4));
  const int sA = l15 + ((lane & 16) << 1);   // q + 32*(g&1)  (words 0,1)
  const int sB = sA + 16;                    //               (words 2,3)
  const bool up = lane >= 32;

  const int ntiles = qtile * 2 + 2;

  #define STAGE(buf, kt)                                                          \
    do {                                                                          \
      const char* ksrc = kg_bh + (size_t)(kt) * 32 * 384;                         \
      const char* vsrc = vg_bh + (size_t)(kt) * 8192;                             \
      _Pragma("unroll")                                                           \
      for (int c = 0; c < 5; ++c) {                                               \
        int cc = wid * 5 + c;                                                     \
        if (cc < 12) GLL16(ksrc + cc * 1024 + lane * 16, &KB[buf][cc * 1024]);    \
        else         GLL16(vsrc + (cc - 12) * 1024 + lane * 16,                   \
                           &VB[buf][(cc - 12) * 1024]);                           \
      }                                                                           \
    } while (0)

  STAGE(0, 0);
  __syncthreads();

  int cur = 0;
  for (int kt = 0; kt < ntiles; ++kt) {
    const int kbase = kt * 32;
    if (kt + 1 < ntiles) STAGE(cur ^ 1, kt + 1);

    // ---- QK^T swapped: C[k][q] = mfma(K-frag, Q-frag) ----
    const char* k0 = (const char*)&KB[cur][0] + l15 * 384;
    const char* k1 = k0 + 16 * 384;
    f32x4 sa0 = (f32x4)0.0f, sa1 = (f32x4)0.0f;
    #pragma unroll
    for (int d0 = 0; d0 < 6; ++d0) {
      const int col = (d0 * 64 + g16) ^ kxor;
      short8 b0 = *(const short8*)(k0 + col);
      sa0 = __builtin_amdgcn_mfma_f32_16x16x32_bf16(b0, aq[d0], sa0, 0, 0, 0);
      short8 b1 = *(const short8*)(k1 + col);
      sa1 = __builtin_amdgcn_mfma_f32_16x16x32_bf16(b1, aq[d0], sa1, 0, 0, 0);
    }

    // ---- scale + causal mask (k = kbase + 16*kc + 4g + r; q = q0w + l15) ----
    const int rem = q0w + l15 - kbase - 4 * g;   // mask if 16*kc + r > rem
    float p[8];
    #pragma unroll
    for (int r = 0; r < 4; ++r) {
      float v0 = sa0[r] * SCL2;
      float v1 = sa1[r] * SCL2;
      p[r]     = (r > rem)      ? -1e30f : v0;
      p[4 + r] = (16 + r > rem) ? -1e30f : v1;
    }

    // ---- in-register online softmax (per-lane scalar state) ----
    float mx = fmaxf(fmaxf(fmaxf(p[0], p[1]), fmaxf(p[2], p[3])),
                     fmaxf(fmaxf(p[4], p[5]), fmaxf(p[6], p[7])));
    mx = fmaxf(mx, __shfl_xor(mx, 16));
    mx = fmaxf(mx, __shfl_xor(mx, 32));
    if (__any(mx > m + 8.0f)) {          // defer-max: rescale only on real growth
      float mn = fmaxf(m, mx);
      float al = hw_exp2(m - mn);
      #pragma unroll
      for (int t = 0; t < 8; ++t) o[t] *= al;
      l *= al; m = mn;
    }
    #pragma unroll
    for (int j = 0; j < 8; ++j) p[j] = hw_exp2(p[j] - m);
    float rs = ((p[0] + p[1]) + (p[2] + p[3])) + ((p[4] + p[5]) + (p[6] + p[7]));
    rs += __shfl_xor(rs, 16);
    rs += __shfl_xor(rs, 32);
    l += rs;

    // ---- P -> B-fragment: cvt_pk + cross-lane exchange (no LDS) ----
    unsigned pk0 = cvtpk(p[0], p[1]);   // (P[16kc+4g+2rp], +1), sw=2kc+rp
    unsigned pk1 = cvtpk(p[2], p[3]);
    unsigned pk2 = cvtpk(p[4], p[5]);
    unsigned pk3 = cvtpk(p[6], p[7]);
    unsigned lo0 = __shfl(pk0, sA), hi0 = __shfl(pk2, sA);
    unsigned lo1 = __shfl(pk1, sA), hi1 = __shfl(pk3, sA);
    unsigned lo2 = __shfl(pk0, sB), hi2 = __shfl(pk2, sB);
    unsigned lo3 = __shfl(pk1, sB), hi3 = __shfl(pk3, sB);
    union { unsigned u[4]; short8 s; } pb;
    pb.u[0] = up ? hi0 : lo0;
    pb.u[1] = up ? hi1 : lo1;
    pb.u[2] = up ? hi2 : lo2;
    pb.u[3] = up ? hi3 : lo3;

    // ---- PV swapped: O^T[dv][q] += mfma(Vt-frag, P-frag) ----
    const char* vbp = (const char*)&VB[cur][0] + vlane;
    #pragma unroll
    for (int t = 0; t < 8; ++t) {
      short8 vb = *(const short8*)(vbp + t * 1024);
      o[t] = __builtin_amdgcn_mfma_f32_16x16x32_bf16(vb, pb.s, o[t], 0, 0, 0);
    }

    __syncthreads();
    cur ^= 1;
  }

  // ---- epilogue: lane holds q = q0w+l15, dv = 16t+4g+r ----
  {
    const int q = q0w + l15;
    const float inv = 1.0f / l;
    float* ob = O + (size_t)((b * S_ + q) * H_ + h) * DV_ + 4 * g;
    #pragma unroll
    for (int t = 0; t < 8; ++t) {
      float4 st = { o[t][0] * inv, o[t][1] * inv, o[t][2] * inv, o[t][3] * inv };
      *(float4*)(ob + 16 * t) = st;
    }
  }
  #undef STAGE
}

// ---------------- fallback (no-prep path) if ws too small ----------------
__launch_bounds__(256)
__global__ void mla_fwd_fb(const float* __restrict__ Q,
                           const float* __restrict__ K,
                           const float* __restrict__ V,
                           float* __restrict__ O) {
  __shared__ __align__(16) unsigned short Kl[2][32][200];
  __shared__ __align__(16) unsigned short Vt[2][128][40];
  __shared__ __align__(16) unsigned short Pl[4][16][40];
  const int tid = threadIdx.x, wid = tid >> 6, lane = tid & 63;
  const int l15 = lane & 15, g = lane >> 4;
  const int qtile = (int)gridDim.x - 1 - (int)blockIdx.x;
  const int bh = blockIdx.y, b = bh >> 4, h = bh & 15;
  const int q0w = qtile * 64 + wid * 16;
  const int krs = H_ * DQ_, vrs = H_ * DV_;
  short8 aq[6];
  {
    const int qoff = ((b * S_ + (q0w + l15)) * H_ + h) * DQ_;
    #pragma unroll
    for (int d0 = 0; d0 < 6; ++d0) {
      const float* p = Q + qoff + d0 * 32 + g * 8;
      float4 f0 = *(const float4*)(p); float4 f1 = *(const float4*)(p + 4);
      short8 a;
      a[0]=f2bf(f0.x); a[1]=f2bf(f0.y); a[2]=f2bf(f0.z); a[3]=f2bf(f0.w);
      a[4]=f2bf(f1.x); a[5]=f2bf(f1.y); a[6]=f2bf(f1.z); a[7]=f2bf(f1.w);
      aq[d0] = a;
    }
  }
  f32x4 o[8];
  #pragma unroll
  for (int t = 0; t < 8; ++t) o[t] = (f32x4)0.0f;
  float m[4], l[4];
  #pragma unroll
  for (int r = 0; r < 4; ++r) { m[r] = -1e30f; l[r] = 0.0f; }
  const int ntiles = qtile * 2 + 2;
  float4 kr[6], vr[4];
  {
    const float* Kb = K + ((b * S_) * H_ + h) * DQ_;
    #pragma unroll
    for (int i = 0; i < 6; ++i) { int idx = i*256+tid; int row = idx/48, c4 = idx%48;
      kr[i] = *(const float4*)(Kb + row*krs + c4*4); }
    const float* Vb = V + ((b * S_) * H_ + h) * DV_;
    #pragma unroll
    for (int i = 0; i < 4; ++i) { int idx = i*256+tid; int row = idx&31, c4 = idx>>5;
      vr[i] = *(const float4*)(Vb + row*vrs + c4*4); }
    #pragma unroll
    for (int i = 0; i < 6; ++i) { int idx = i*256+tid; int row = idx/48, c4 = idx%48;
      ushort4 u; u.x=f2bf(kr[i].x); u.y=f2bf(kr[i].y); u.z=f2bf(kr[i].z); u.w=f2bf(kr[i].w);
      *(ushort4*)&Kl[0][row][c4*4] = u; }
    #pragma unroll
    for (int i = 0; i < 4; ++i) { int idx = i*256+tid; int row = idx&31, c4 = idx>>5;
      Vt[0][c4*4+0][row]=f2bf(vr[i].x); Vt[0][c4*4+1][row]=f2bf(vr[i].y);
      Vt[0][c4*4+2][row]=f2bf(vr[i].z); Vt[0][c4*4+3][row]=f2bf(vr[i].w); }
  }
  __syncthreads();
  int cur = 0;
  for (int kt = 0; kt < ntiles; ++kt) {
    const int kbase = kt * 32;
    const bool pf = (kt + 1 < ntiles);
    if (pf) {
      const int nb = kbase + 32;
      const float* Kb = K + ((b*S_+nb)*H_ + h)*DQ_;
      #pragma unroll
      for (int i = 0; i < 6; ++i) { int idx = i*256+tid; int row = idx/48, c4 = idx%48;
        kr[i] = *(const float4*)(Kb + row*krs + c4*4); }
      const float* Vb = V + ((b*S_+nb)*H_ + h)*DV_;
      #pragma unroll
      for (int i = 0; i < 4; ++i) { int idx = i*256+tid; int row = idx&31, c4 = idx>>5;
        vr[i] = *(const float4*)(Vb + row*vrs + c4*4); }
    }
    f32x4 sa0 = (f32x4)0.0f, sa1 = (f32x4)0.0f;
    #pragma unroll
    for (int d0 = 0; d0 < 6; ++d0) {
      short8 b0 = *(const short8*)&Kl[cur][l15][d0*32 + g*8];
      sa0 = __builtin_amdgcn_mfma_f32_16x16x32_bf16(aq[d0], b0, sa0, 0, 0, 0);
      short8 b1 = *(const short8*)&Kl[cur][16+l15][d0*32 + g*8];
      sa1 = __builtin_amdgcn_mfma_f32_16x16x32_bf16(aq[d0], b1, sa1, 0, 0, 0);
    }
    float p0[4], p1[4];
    #pragma unroll
    for (int r = 0; r < 4; ++r) {
      const int qg = q0w + 4*g + r;
      float s0 = sa0[r]*SCL2, s1 = sa1[r]*SCL2;
      if (kbase + l15 > qg) s0 = -1e30f;
      if (kbase + 16 + l15 > qg) s1 = -1e30f;
      p0[r] = s0; p1[r] = s1;
    }
    #pragma unroll
    for (int r = 0; r < 4; ++r) {
      float rm = fmaxf(p0[r], p1[r]);
      #pragma unroll
      for (int off = 1; off < 16; off <<= 1) rm = fmaxf(rm, __shfl_xor(rm, off));
      float mn = fmaxf(m[r], rm);
      float alpha = exp2f(m[r] - mn); m[r] = mn;
      float e0 = exp2f(p0[r] - mn), e1 = exp2f(p1[r] - mn);
      p0[r] = e0; p1[r] = e1;
      float rsum = e0 + e1;
      #pragma unroll
      for (int off = 1; off < 16; off <<= 1) rsum += __shfl_xor(rsum, off);
      l[r] = l[r]*alpha + rsum;
      #pragma unroll
      for (int t = 0; t < 8; ++t) o[t][r] *= alpha;
    }
    #pragma unroll
    for (int r = 0; r < 4; ++r) {
      Pl[wid][4*g+r][l15]      = f2bf(p0[r]);
      Pl[wid][4*g+r][16+l15]   = f2bf(p1[r]);
    }
    short8 pa = *(const short8*)&Pl[wid][l15][g*8];
    #pragma unroll
    for (int t = 0; t < 8; ++t) {
      short8 vb = *(const short8*)&Vt[cur][t*16+l15][g*8];
      o[t] = __builtin_amdgcn_mfma_f32_16x16x32_bf16(pa, vb, o[t], 0, 0, 0);
    }
    if (pf) {
      #pragma unroll
      for (int i = 0; i < 6; ++i) { int idx = i*256+tid; int row = idx/48, c4 = idx%48;
        ushort4 u; u.x=f2bf(kr[i].x); u.y=f2bf(kr[i].y); u.z=f2bf(kr[i].z); u.w=f2bf(kr[i].w);
        *(ushort4*)&Kl[cur^1][row][c4*4] = u; }
      #pragma unroll
      for (int i = 0; i < 4; ++i) { int idx = i*256+tid; int row = idx&31, c4 = idx>>5;
        Vt[cur^1][c4*4+0][row]=f2bf(vr[i].x); Vt[cur^1][c4*4+1][row]=f2bf(vr[i].y);
        Vt[cur^1][c4*4+2][row]=f2bf(vr[i].z); Vt[cur^1][c4*4+3][row]=f2bf(vr[i].w); }
    }
    __syncthreads();
    cur ^= 1;
  }
  #pragma unroll
  for (int r = 0; r < 4; ++r) {
    const int qg = q0w + 4*g + r;
    const float inv = 1.0f / l[r];
    #pragma unroll
    for (int t = 0; t < 8; ++t)
      O[((b*S_+qg)*H_ + h)*DV_ + t*16 + l15] = o[t][r] * inv;
  }
}

extern "C" void kernel_launch(void* const* d_in, const int* in_sizes, int n_in,
                              void* d_out, int out_size, void* d_ws, size_t ws_size,
                              hipStream_t stream) {
  const float* q = (const float*)d_in[0];
  const float* k = (const float*)d_in[1];
  const float* v = (const float*)d_in[2];
  float* out = (float*)d_out;

  if (ws_size >= KG_BYTES + VG_BYTES) {
    unsigned short* Kg = (unsigned short*)d_ws;
    unsigned short* Vg = (unsigned short*)((char*)d_ws + KG_BYTES);
    prep_k<<<dim3((B_ * S_ * H_ * 48) / 256), dim3(256), 0, stream>>>(k, Kg);
    prep_v<<<dim3(B_ * H_ * 64), dim3(256), 0, stream>>>(v, Vg);
    mla_fwd<<<dim3(1024), dim3(256), 0, stream>>>(q, Kg, Vg, out);
  } else {
    dim3 grid(S_ / 64, B_ * H_);
    mla_fwd_fb<<<grid, dim3(256), 0, stream>>>(q, k, v, out);
  }
}

// Round 5
// 107.167 us; speedup vs baseline: 3.7489x; 1.4762x over previous
//
#include <hip/hip_runtime.h>

#define B_ 2
#define S_ 2048
#define H_ 16
#define DQ_ 192
#define DV_ 128
// log2(e)/sqrt(192)
#define SCL2 0.10411163731422901f

typedef short short8 __attribute__((ext_vector_type(8)));
typedef float f32x4 __attribute__((ext_vector_type(4)));

#define KG_BYTES ((size_t)25165824)   // B*H*S*DQ*2
#define VG_BYTES ((size_t)16777216)   // B*H*DV*S*2

__device__ __forceinline__ unsigned short f2bf(float f) {
  union { float f; unsigned u; } x; x.f = f;
  unsigned r = x.u + 0x7FFFu + ((x.u >> 16) & 1u);   // RNE
  return (unsigned short)(r >> 16);
}

__device__ __forceinline__ float hw_exp2(float x) {
  float r; asm("v_exp_f32 %0, %1" : "=v"(r) : "v"(x)); return r;
}
__device__ __forceinline__ unsigned cvtpk(float lo, float hi) {
  unsigned r; asm("v_cvt_pk_bf16_f32 %0, %1, %2" : "=v"(r) : "v"(lo), "v"(hi)); return r;
}

#define GLL16(src, dst) \
  __builtin_amdgcn_global_load_lds((const __attribute__((address_space(1))) void*)(src), \
                                   (__attribute__((address_space(3))) void*)(dst), 16, 0, 0)

// ---------------- pre-pass: K -> bf16, row-swizzled [bh][s][384B] ----------------
__global__ __launch_bounds__(256) void prep_k(const float* __restrict__ K,
                                              unsigned short* __restrict__ Kg) {
  int idx = blockIdx.x * 256 + threadIdx.x;
  int d4 = idx % 48; int r = idx / 48;
  int h = r % H_; r /= H_;
  int s = r % S_; int b = r / S_;
  float4 f = *(const float4*)(K + (size_t)((b * S_ + s) * H_ + h) * DQ_ + d4 * 4);
  ushort4 u; u.x = f2bf(f.x); u.y = f2bf(f.y); u.z = f2bf(f.z); u.w = f2bf(f.w);
  size_t rowb = (size_t)((b * H_ + h) * S_ + s) * (DQ_ * 2);
  int cb = (d4 * 8) ^ ((s & 7) << 4);
  *(ushort4*)((char*)Kg + rowb + cb) = u;
}

// ------- pre-pass: V -> bf16, transposed+swizzled 8KB tiles [bh][sb][tile] -------
__global__ __launch_bounds__(256) void prep_v(const float* __restrict__ V,
                                              unsigned short* __restrict__ Vg) {
  __shared__ float lv[32][132];
  int blk = blockIdx.x;
  int sb = blk & 63, bh = blk >> 6;
  int b = bh >> 4, h = bh & 15;
  int tid = threadIdx.x;
  #pragma unroll
  for (int i = 0; i < 4; ++i) {
    int idx = i * 256 + tid;
    int s_in = idx >> 5, d4 = idx & 31;
    float4 f = *(const float4*)(V + (size_t)((b * S_ + sb * 32 + s_in) * H_ + h) * DV_ + d4 * 4);
    lv[s_in][d4 * 4 + 0] = f.x; lv[s_in][d4 * 4 + 1] = f.y;
    lv[s_in][d4 * 4 + 2] = f.z; lv[s_in][d4 * 4 + 3] = f.w;
  }
  __syncthreads();
  char* base = (char*)Vg + (size_t)blk * 8192;
  #pragma unroll
  for (int j = 0; j < 2; ++j) {
    int ob = tid * 32 + j * 16;
    int row = ob >> 7, cb = ob & 127;
    int orig = cb ^ ((row & 7) << 4);
    int d = row * 2 + (orig >> 6);
    int s0 = (orig & 63) >> 1;
    short8 u;
    #pragma unroll
    for (int e = 0; e < 8; ++e) u[e] = (short)f2bf(lv[s0 + e][d]);
    *(short8*)(base + ob) = u;
  }
}

// ---------------- main: flash MLA, swapped QK^T, balanced-quad scheduling ----------------
__launch_bounds__(256, 4)
__global__ void mla_fwd(const float* __restrict__ Q,
                        const unsigned short* __restrict__ Kg,
                        const unsigned short* __restrict__ Vg,
                        float* __restrict__ O) {
  // unified staging buffer: [buf][ K 12288B | V 8192B ] -> 40960B total, 4 blocks/CU
  __shared__ __align__(16) unsigned char SB[2][20480];

  const int tid  = threadIdx.x;
  const int wid  = tid >> 6;
  const int lane = tid & 63;
  const int l15  = lane & 15;
  const int g    = lane >> 4;

  // ---- balanced-quad mapping ----
  // XCD x = i&7; li = i>>3; c = li&31 (CU slot), s = li>>5 (round 0..3).
  // Blocks co-resident on a CU get qtiles {31-j, j, 16+j, 15-j}: iter sum = 132 for all j.
  const int i  = blockIdx.x;
  const int x  = i & 7;
  const int li = i >> 3;
  const int c  = li & 31;
  const int s  = li >> 5;
  const int j  = c & 7;
  const int t  = c >> 3;
  const int bh = x * 4 + t;
  const int qtile = (s == 0) ? (31 - j) : (s == 1) ? j : (s == 2) ? (16 + j) : (15 - j);
  const int b  = bh >> 4, h = bh & 15;
  const int q0w = qtile * 64 + wid * 16;

  const char* kg_bh = (const char*)Kg + (size_t)bh * S_ * (DQ_ * 2);
  const char* vg_bh = (const char*)Vg + (size_t)bh * 64 * 8192;

  // ---- hoist Q fragments (B-operand of swapped QK^T) ----
  short8 aq[6];
  {
    const size_t qoff = (size_t)((b * S_ + (q0w + l15)) * H_ + h) * DQ_;
    #pragma unroll
    for (int d0 = 0; d0 < 6; ++d0) {
      const float* p = Q + qoff + d0 * 32 + g * 8;
      float4 f0 = *(const float4*)(p);
      float4 f1 = *(const float4*)(p + 4);
      short8 a;
      a[0] = f2bf(f0.x); a[1] = f2bf(f0.y); a[2] = f2bf(f0.z); a[3] = f2bf(f0.w);
      a[4] = f2bf(f1.x); a[5] = f2bf(f1.y); a[6] = f2bf(f1.z); a[7] = f2bf(f1.w);
      aq[d0] = a;
    }
  }

  f32x4 o[8];   // O^T: o[t][r] = O[dv=16t+4g+r][q=l15]
  #pragma unroll
  for (int t2 = 0; t2 < 8; ++t2) o[t2] = (f32x4)0.0f;
  float m = -1e30f, l = 0.0f;

  const int kxor = (l15 & 7) << 4;
  const int g16  = g * 16;
  const int vlane = 12288 + (l15 >> 1) * 128 +
                    ((((l15 & 1) * 64) + g16) ^ (((l15 >> 1) & 7) << 4));
  const int sA = l15 + ((lane & 16) << 1);
  const int sB = sA + 16;
  const bool up = lane >= 32;

  const int ntiles = qtile * 2 + 2;

  // ---- persistent staging pointers: 5 chunks/wave, affine in kt ----
  const char* sp[5];
  int sdo[5], sst[5];
  #pragma unroll
  for (int ci = 0; ci < 5; ++ci) {
    int cc = wid * 5 + ci;
    if (cc < 12) { sp[ci] = kg_bh + cc * 1024 + lane * 16;        sdo[ci] = cc * 1024;          sst[ci] = 12288; }
    else         { sp[ci] = vg_bh + (cc - 12) * 1024 + lane * 16; sdo[ci] = 12288 + (cc - 12) * 1024; sst[ci] = 8192; }
  }

  #define STAGE(buf)                                         \
    do {                                                     \
      _Pragma("unroll")                                      \
      for (int ci = 0; ci < 5; ++ci) {                       \
        GLL16(sp[ci], &SB[buf][sdo[ci]]);                    \
        sp[ci] += sst[ci];                                   \
      }                                                      \
    } while (0)

  STAGE(0);
  __syncthreads();

  int cur = 0;
  for (int kt = 0; kt < ntiles; ++kt) {
    const int kbase = kt * 32;
    if (kt + 1 < ntiles) STAGE(cur ^ 1);

    // ---- QK^T swapped: C[k][q] = mfma(K-frag, Q-frag) ----
    const char* k0 = (const char*)&SB[cur][0] + l15 * 384;
    const char* k1 = k0 + 16 * 384;
    f32x4 sa0 = (f32x4)0.0f, sa1 = (f32x4)0.0f;
    __builtin_amdgcn_s_setprio(1);
    #pragma unroll
    for (int d0 = 0; d0 < 6; ++d0) {
      const int col = (d0 * 64 + g16) ^ kxor;
      short8 b0 = *(const short8*)(k0 + col);
      sa0 = __builtin_amdgcn_mfma_f32_16x16x32_bf16(b0, aq[d0], sa0, 0, 0, 0);
      short8 b1 = *(const short8*)(k1 + col);
      sa1 = __builtin_amdgcn_mfma_f32_16x16x32_bf16(b1, aq[d0], sa1, 0, 0, 0);
    }
    __builtin_amdgcn_s_setprio(0);

    // ---- scale + (wave-uniform skippable) causal mask ----
    float p[8];
    #pragma unroll
    for (int r = 0; r < 4; ++r) {
      p[r]     = sa0[r] * SCL2;
      p[4 + r] = sa1[r] * SCL2;
    }
    if (kbase + 31 > q0w) {                     // only last ~2 tiles per wave
      const int rem = q0w + l15 - kbase - 4 * g;
      #pragma unroll
      for (int r = 0; r < 4; ++r) {
        if (r > rem)      p[r]     = -1e30f;
        if (16 + r > rem) p[4 + r] = -1e30f;
      }
    }

    // ---- in-register online softmax (per-lane scalar state) ----
    float mx = fmaxf(fmaxf(fmaxf(p[0], p[1]), fmaxf(p[2], p[3])),
                     fmaxf(fmaxf(p[4], p[5]), fmaxf(p[6], p[7])));
    mx = fmaxf(mx, __shfl_xor(mx, 16));
    mx = fmaxf(mx, __shfl_xor(mx, 32));
    if (__any(mx > m + 8.0f)) {
      float mn = fmaxf(m, mx);
      float al = hw_exp2(m - mn);
      #pragma unroll
      for (int t2 = 0; t2 < 8; ++t2) o[t2] *= al;
      l *= al; m = mn;
    }
    #pragma unroll
    for (int jj = 0; jj < 8; ++jj) p[jj] = hw_exp2(p[jj] - m);
    float rs = ((p[0] + p[1]) + (p[2] + p[3])) + ((p[4] + p[5]) + (p[6] + p[7]));
    rs += __shfl_xor(rs, 16);
    rs += __shfl_xor(rs, 32);
    l += rs;

    // ---- P -> B-fragment: cvt_pk + cross-lane exchange (no LDS) ----
    unsigned pk0 = cvtpk(p[0], p[1]);
    unsigned pk1 = cvtpk(p[2], p[3]);
    unsigned pk2 = cvtpk(p[4], p[5]);
    unsigned pk3 = cvtpk(p[6], p[7]);
    unsigned lo0 = __shfl(pk0, sA), hi0 = __shfl(pk2, sA);
    unsigned lo1 = __shfl(pk1, sA), hi1 = __shfl(pk3, sA);
    unsigned lo2 = __shfl(pk0, sB), hi2 = __shfl(pk2, sB);
    unsigned lo3 = __shfl(pk1, sB), hi3 = __shfl(pk3, sB);
    union { unsigned u[4]; short8 s; } pb;
    pb.u[0] = up ? hi0 : lo0;
    pb.u[1] = up ? hi1 : lo1;
    pb.u[2] = up ? hi2 : lo2;
    pb.u[3] = up ? hi3 : lo3;

    // ---- PV swapped: O^T[dv][q] += mfma(Vt-frag, P-frag) ----
    const char* vbp = (const char*)&SB[cur][0] + vlane;
    __builtin_amdgcn_s_setprio(1);
    #pragma unroll
    for (int t2 = 0; t2 < 8; ++t2) {
      short8 vb = *(const short8*)(vbp + t2 * 1024);
      o[t2] = __builtin_amdgcn_mfma_f32_16x16x32_bf16(vb, pb.s, o[t2], 0, 0, 0);
    }
    __builtin_amdgcn_s_setprio(0);

    __syncthreads();
    cur ^= 1;
  }

  // ---- epilogue: lane holds q = q0w+l15, dv = 16t+4g+r ----
  {
    const int q = q0w + l15;
    const float inv = 1.0f / l;
    float* ob = O + (size_t)((b * S_ + q) * H_ + h) * DV_ + 4 * g;
    #pragma unroll
    for (int t2 = 0; t2 < 8; ++t2) {
      float4 st = { o[t2][0] * inv, o[t2][1] * inv, o[t2][2] * inv, o[t2][3] * inv };
      *(float4*)(ob + 16 * t2) = st;
    }
  }
  #undef STAGE
}

// ---------------- fallback (no-prep path) if ws too small ----------------
__launch_bounds__(256)
__global__ void mla_fwd_fb(const float* __restrict__ Q,
                           const float* __restrict__ K,
                           const float* __restrict__ V,
                           float* __restrict__ O) {
  __shared__ __align__(16) unsigned short Kl[2][32][200];
  __shared__ __align__(16) unsigned short Vt[2][128][40];
  __shared__ __align__(16) unsigned short Pl[4][16][40];
  const int tid = threadIdx.x, wid = tid >> 6, lane = tid & 63;
  const int l15 = lane & 15, g = lane >> 4;
  const int qtile = (int)gridDim.x - 1 - (int)blockIdx.x;
  const int bh = blockIdx.y, b = bh >> 4, h = bh & 15;
  const int q0w = qtile * 64 + wid * 16;
  const int krs = H_ * DQ_, vrs = H_ * DV_;
  short8 aq[6];
  {
    const int qoff = ((b * S_ + (q0w + l15)) * H_ + h) * DQ_;
    #pragma unroll
    for (int d0 = 0; d0 < 6; ++d0) {
      const float* p = Q + qoff + d0 * 32 + g * 8;
      float4 f0 = *(const float4*)(p); float4 f1 = *(const float4*)(p + 4);
      short8 a;
      a[0]=f2bf(f0.x); a[1]=f2bf(f0.y); a[2]=f2bf(f0.z); a[3]=f2bf(f0.w);
      a[4]=f2bf(f1.x); a[5]=f2bf(f1.y); a[6]=f2bf(f1.z); a[7]=f2bf(f1.w);
      aq[d0] = a;
    }
  }
  f32x4 o[8];
  #pragma unroll
  for (int t = 0; t < 8; ++t) o[t] = (f32x4)0.0f;
  float m[4], l[4];
  #pragma unroll
  for (int r = 0; r < 4; ++r) { m[r] = -1e30f; l[r] = 0.0f; }
  const int ntiles = qtile * 2 + 2;
  float4 kr[6], vr[4];
  {
    const float* Kb = K + ((b * S_) * H_ + h) * DQ_;
    #pragma unroll
    for (int i = 0; i < 6; ++i) { int idx = i*256+tid; int row = idx/48, c4 = idx%48;
      kr[i] = *(const float4*)(Kb + row*krs + c4*4); }
    const float* Vb = V + ((b * S_) * H_ + h) * DV_;
    #pragma unroll
    for (int i = 0; i < 4; ++i) { int idx = i*256+tid; int row = idx&31, c4 = idx>>5;
      vr[i] = *(const float4*)(Vb + row*vrs + c4*4); }
    #pragma unroll
    for (int i = 0; i < 6; ++i) { int idx = i*256+tid; int row = idx/48, c4 = idx%48;
      ushort4 u; u.x=f2bf(kr[i].x); u.y=f2bf(kr[i].y); u.z=f2bf(kr[i].z); u.w=f2bf(kr[i].w);
      *(ushort4*)&Kl[0][row][c4*4] = u; }
    #pragma unroll
    for (int i = 0; i < 4; ++i) { int idx = i*256+tid; int row = idx&31, c4 = idx>>5;
      Vt[0][c4*4+0][row]=f2bf(vr[i].x); Vt[0][c4*4+1][row]=f2bf(vr[i].y);
      Vt[0][c4*4+2][row]=f2bf(vr[i].z); Vt[0][c4*4+3][row]=f2bf(vr[i].w); }
  }
  __syncthreads();
  int cur = 0;
  for (int kt = 0; kt < ntiles; ++kt) {
    const int kbase = kt * 32;
    const bool pf = (kt + 1 < ntiles);
    if (pf) {
      const int nb = kbase + 32;
      const float* Kb = K + ((b*S_+nb)*H_ + h)*DQ_;
      #pragma unroll
      for (int i = 0; i < 6; ++i) { int idx = i*256+tid; int row = idx/48, c4 = idx%48;
        kr[i] = *(const float4*)(Kb + row*krs + c4*4); }
      const float* Vb = V + ((b*S_+nb)*H_ + h)*DV_;
      #pragma unroll
      for (int i = 0; i < 4; ++i) { int idx = i*256+tid; int row = idx&31, c4 = idx>>5;
        vr[i] = *(const float4*)(Vb + row*vrs + c4*4); }
    }
    f32x4 sa0 = (f32x4)0.0f, sa1 = (f32x4)0.0f;
    #pragma unroll
    for (int d0 = 0; d0 < 6; ++d0) {
      short8 b0 = *(const short8*)&Kl[cur][l15][d0*32 + g*8];
      sa0 = __builtin_amdgcn_mfma_f32_16x16x32_bf16(aq[d0], b0, sa0, 0, 0, 0);
      short8 b1 = *(const short8*)&Kl[cur][16+l15][d0*32 + g*8];
      sa1 = __builtin_amdgcn_mfma_f32_16x16x32_bf16(aq[d0], b1, sa1, 0, 0, 0);
    }
    float p0[4], p1[4];
    #pragma unroll
    for (int r = 0; r < 4; ++r) {
      const int qg = q0w + 4*g + r;
      float s0 = sa0[r]*SCL2, s1 = sa1[r]*SCL2;
      if (kbase + l15 > qg) s0 = -1e30f;
      if (kbase + 16 + l15 > qg) s1 = -1e30f;
      p0[r] = s0; p1[r] = s1;
    }
    #pragma unroll
    for (int r = 0; r < 4; ++r) {
      float rm = fmaxf(p0[r], p1[r]);
      #pragma unroll
      for (int off = 1; off < 16; off <<= 1) rm = fmaxf(rm, __shfl_xor(rm, off));
      float mn = fmaxf(m[r], rm);
      float alpha = exp2f(m[r] - mn); m[r] = mn;
      float e0 = exp2f(p0[r] - mn), e1 = exp2f(p1[r] - mn);
      p0[r] = e0; p1[r] = e1;
      float rsum = e0 + e1;
      #pragma unroll
      for (int off = 1; off < 16; off <<= 1) rsum += __shfl_xor(rsum, off);
      l[r] = l[r]*alpha + rsum;
      #pragma unroll
      for (int t = 0; t < 8; ++t) o[t][r] *= alpha;
    }
    #pragma unroll
    for (int r = 0; r < 4; ++r) {
      Pl[wid][4*g+r][l15]      = f2bf(p0[r]);
      Pl[wid][4*g+r][16+l15]   = f2bf(p1[r]);
    }
    short8 pa = *(const short8*)&Pl[wid][l15][g*8];
    #pragma unroll
    for (int t = 0; t < 8; ++t) {
      short8 vb = *(const short8*)&Vt[cur][t*16+l15][g*8];
      o[t] = __builtin_amdgcn_mfma_f32_16x16x32_bf16(pa, vb, o[t], 0, 0, 0);
    }
    if (pf) {
      #pragma unroll
      for (int i = 0; i < 6; ++i) { int idx = i*256+tid; int row = idx/48, c4 = idx%48;
        ushort4 u; u.x=f2bf(kr[i].x); u.y=f2bf(kr[i].y); u.z=f2bf(kr[i].z); u.w=f2bf(kr[i].w);
        *(ushort4*)&Kl[cur^1][row][c4*4] = u; }
      #pragma unroll
      for (int i = 0; i < 4; ++i) { int idx = i*256+tid; int row = idx&31, c4 = idx>>5;
        Vt[cur^1][c4*4+0][row]=f2bf(vr[i].x); Vt[cur^1][c4*4+1][row]=f2bf(vr[i].y);
        Vt[cur^1][c4*4+2][row]=f2bf(vr[i].z); Vt[cur^1][c4*4+3][row]=f2bf(vr[i].w); }
    }
    __syncthreads();
    cur ^= 1;
  }
  #pragma unroll
  for (int r = 0; r < 4; ++r) {
    const int qg = q0w + 4*g + r;
    const float inv = 1.0f / l[r];
    #pragma unroll
    for (int t = 0; t < 8; ++t)
      O[((b*S_+qg)*H_ + h)*DV_ + t*16 + l15] = o[t][r] * inv;
  }
}

extern "C" void kernel_launch(void* const* d_in, const int* in_sizes, int n_in,
                              void* d_out, int out_size, void* d_ws, size_t ws_size,
                              hipStream_t stream) {
  const float* q = (const float*)d_in[0];
  const float* k = (const float*)d_in[1];
  const float* v = (const float*)d_in[2];
  float* out = (float*)d_out;

  if (ws_size >= KG_BYTES + VG_BYTES) {
    unsigned short* Kg = (unsigned short*)d_ws;
    unsigned short* Vg = (unsigned short*)((char*)d_ws + KG_BYTES);
    prep_k<<<dim3((B_ * S_ * H_ * 48) / 256), dim3(256), 0, stream>>>(k, Kg);
    prep_v<<<dim3(B_ * H_ * 64), dim3(256), 0, stream>>>(v, Vg);
    mla_fwd<<<dim3(1024), dim3(256), 0, stream>>>(q, Kg, Vg, out);
  } else {
    dim3 grid(S_ / 64, B_ * H_);
    mla_fwd_fb<<<grid, dim3(256), 0, stream>>>(q, k, v, out);
  }
}